// Round 9
// baseline (173.383 us; speedup 1.0000x reference)
//
#include <hip/hip_runtime.h>

// y[e, o] = sum_i weight[widx[e]][o][i] * values[iidx[e]][i]
// E = 1e6, N_W = 1024, D_IN = D_OUT = 16, fp32.
//
// R1: weight gather latency-bound -> 137 us kernel.
// R2: global-atomic scatter serialized -> 203 us.
// R6/R7/R8: three different W strategies (LDS re-read w/ conflicts, sunk
//     loads, asm-pinned VGPRs) ALL land 58-63 us -> W access is not the
//     wall. VALUBusy 20% matches FMA issue arithmetic; VMEM/L2 rates ~0.1/cy.
//     Wall = latency x concurrency: occupancy 51%, small blocks (244 conns)
//     pay serial startup (offsets -> W -> barrier) for ~4 iters of work.
// R9: concurrency attack:
//     - SEG=2 (2048 blocks, 488 conns, ~8 iters/block)
//     - no launch_bounds min-waves (let allocator go low-VGPR, 8 waves/EU)
//     - NO LDS, NO barrier: lane i loads W row i direct from global (L2-hot)

#define D 16
#define NWMAX 1024
#define NB 256      // sort chunks
#define BTS 1024    // sort-phase threads per block
#define SEG 2

// ---------------- fallback naive kernel (R1, 137us) ----------------
__global__ __launch_bounds__(256) void linear_gather_mv(
    const float* __restrict__ values, const float* __restrict__ weight,
    const int* __restrict__ input_idx, const int* __restrict__ weight_idx,
    float* __restrict__ out, int E)
{
    int tid = blockIdx.x * blockDim.x + threadIdx.x;
    int e = tid >> 2;
    int j = tid & 3;
    if (e >= E) return;
    int ii = input_idx[e];
    int wi = weight_idx[e];
    const float4* xp = (const float4*)(values + (long long)ii * D);
    float4 x0 = xp[0], x1 = xp[1], x2 = xp[2], x3 = xp[3];
    const float4* wp = (const float4*)(weight + (long long)wi * (D * D) + j * (4 * D));
    float4 acc;
    float* accp = (float*)&acc;
    #pragma unroll
    for (int r = 0; r < 4; ++r) {
        float4 w0 = wp[r * 4 + 0], w1 = wp[r * 4 + 1], w2 = wp[r * 4 + 2], w3 = wp[r * 4 + 3];
        accp[r] = w0.x * x0.x + w0.y * x0.y + w0.z * x0.z + w0.w * x0.w
                + w1.x * x1.x + w1.y * x1.y + w1.z * x1.z + w1.w * x1.w
                + w2.x * x2.x + w2.y * x2.y + w2.z * x2.z + w2.w * x2.w
                + w3.x * x3.x + w3.y * x3.y + w3.z * x3.z + w3.w * x3.w;
    }
    ((float4*)out)[(long long)e * 4 + j] = acc;
}

// ---------------- phase 1: per-block private histograms ----------------
__global__ __launch_bounds__(BTS) void hist_blocks(
    const int* __restrict__ widx, int E, int chunk,
    int* __restrict__ hist2d, int NW)
{
    __shared__ int lh[NWMAX];
    for (int i = threadIdx.x; i < NW; i += BTS) lh[i] = 0;
    __syncthreads();
    int s0 = blockIdx.x * chunk;
    int s1 = min(E, s0 + chunk);
    for (int e = s0 + threadIdx.x; e < s1; e += BTS)
        atomicAdd(&lh[widx[e]], 1);
    __syncthreads();
    int* row = hist2d + (long long)blockIdx.x * NW;
    for (int i = threadIdx.x; i < NW; i += BTS) row[i] = lh[i];
}

// ------- phase 2a: per-bin exclusive scan across blocks (parallel) -------
__global__ __launch_bounds__(NB) void scan_per_bin(
    int* __restrict__ hist2d, int* __restrict__ total, int NW)
{
    __shared__ int buf[2 * NB];
    int b = blockIdx.x;   // bin
    int t = threadIdx.x;  // sort-block index
    int v = hist2d[(long long)t * NW + b];
    buf[t] = v;
    __syncthreads();
    int pin = 0;
    for (int off = 1; off < NB; off <<= 1) {
        int x = buf[pin * NB + t];
        if (t >= off) x += buf[pin * NB + t - off];
        buf[(1 - pin) * NB + t] = x;
        pin = 1 - pin;
        __syncthreads();
    }
    int incl = buf[pin * NB + t];
    hist2d[(long long)t * NW + b] = incl - v;
    if (t == NB - 1) total[b] = incl;
}

// ---------------- phase 2b: scan over bins -> bucket offsets ----------------
__global__ __launch_bounds__(1024) void scan_bins(
    const int* __restrict__ total, int* __restrict__ offsets, int NW)
{
    __shared__ int buf[2 * NWMAX];
    int t = threadIdx.x;
    int v = (t < NW) ? total[t] : 0;
    buf[t] = v;
    __syncthreads();
    int pin = 0;
    for (int off = 1; off < NWMAX; off <<= 1) {
        int x = buf[pin * NWMAX + t];
        if (t >= off) x += buf[pin * NWMAX + t - off];
        buf[(1 - pin) * NWMAX + t] = x;
        pin = 1 - pin;
        __syncthreads();
    }
    int incl = buf[pin * NWMAX + t];
    if (t < NW) {
        offsets[t + 1] = incl;
        if (t == 0) offsets[0] = 0;
    }
}

// ---------------- phase 3: deterministic scatter, LDS cursors ----------------
__global__ __launch_bounds__(BTS) void scatter_det(
    const int* __restrict__ widx, const int* __restrict__ iidx, int E, int chunk,
    const int* __restrict__ hist2d, const int* __restrict__ offsets,
    int2* __restrict__ perm, int NW)
{
    __shared__ int cur[NWMAX];
    int p = blockIdx.x;
    const int* row = hist2d + (long long)p * NW;
    for (int i = threadIdx.x; i < NW; i += BTS)
        cur[i] = offsets[i] + row[i];
    __syncthreads();
    int s0 = p * chunk;
    int s1 = min(E, s0 + chunk);
    for (int e = s0 + threadIdx.x; e < s1; e += BTS) {
        int wi = widx[e];
        int pos = atomicAdd(&cur[wi], 1);
        perm[pos] = make_int2(e, iidx[e]);
    }
}

#define ROWDOT(X0, X1, X2, X3)                                   \
    (w0.x*X0.x + w0.y*X0.y + w0.z*X0.z + w0.w*X0.w               \
   + w1.x*X1.x + w1.y*X1.y + w1.z*X1.z + w1.w*X1.w               \
   + w2.x*X2.x + w2.y*X2.y + w2.z*X2.z + w2.w*X2.w               \
   + w3.x*X3.x + w3.y*X3.y + w3.z*X3.z + w3.w*X3.w)

// ---- phase 4: 16 lanes/conn, lane i = output row i. W row loaded direct
// from global (L2-hot, 4MB total). No LDS, no barrier, no launch-bounds
// pin -> max occupancy. SEG=2: 2048 blocks, ~488 conns each.
__global__ __launch_bounds__(256) void bucket_mv(
    const float* __restrict__ values, const float* __restrict__ weight,
    const int* __restrict__ offsets, const int2* __restrict__ perm,
    float* __restrict__ out)
{
    int b = blockIdx.x;
    int lo = offsets[b], hi = offsets[b + 1];
    int cnt = hi - lo;
    if (cnt == 0) return;
    int per = (cnt + SEG - 1) / SEG;
    int s0 = lo + blockIdx.y * per;
    int s1 = min(hi, s0 + per);
    if (s0 >= s1) return;

    int i  = threadIdx.x & 15;   // output row this lane owns
    int sg = threadIdx.x >> 4;   // subgroup (0..15)

    // my W row direct from global; 16 distinct 64B rows per block, L2-hot
    const float4* wr = (const float4*)(weight + (long long)b * (D * D) + i * D);
    float4 w0 = wr[0], w1 = wr[1], w2 = wr[2], w3 = wr[3];

    // subgroup handles 4 contiguous conns per iter; block covers 64/iter
    for (int k0 = s0 + 4 * sg; k0 < s1; k0 += 64) {
        int k1 = k0 + 1, k2 = k0 + 2, k3 = k0 + 3;
        bool h1 = k1 < s1, h2 = k2 < s1, h3 = k3 < s1;
        int2 pA = perm[k0];
        int2 pB = h1 ? perm[k1] : pA;
        int2 pC = h2 ? perm[k2] : pA;
        int2 pD = h3 ? perm[k3] : pA;

        // 4 independent gather chains
        const float4* xa = (const float4*)(values + (long long)pA.y * D);
        const float4* xb = (const float4*)(values + (long long)pB.y * D);
        const float4* xc = (const float4*)(values + (long long)pC.y * D);
        const float4* xd = (const float4*)(values + (long long)pD.y * D);
        float4 a0 = xa[0], a1 = xa[1], a2 = xa[2], a3 = xa[3];
        float4 b0 = xb[0], b1 = xb[1], b2 = xb[2], b3 = xb[3];
        float4 c0 = xc[0], c1 = xc[1], c2 = xc[2], c3 = xc[3];
        float4 d0 = xd[0], d1 = xd[1], d2 = xd[2], d3 = xd[3];

        out[(long long)pA.x * D + i] = ROWDOT(a0, a1, a2, a3);
        if (h1) out[(long long)pB.x * D + i] = ROWDOT(b0, b1, b2, b3);
        if (h2) out[(long long)pC.x * D + i] = ROWDOT(c0, c1, c2, c3);
        if (h3) out[(long long)pD.x * D + i] = ROWDOT(d0, d1, d2, d3);
    }
}

extern "C" void kernel_launch(void* const* d_in, const int* in_sizes, int n_in,
                              void* d_out, int out_size, void* d_ws, size_t ws_size,
                              hipStream_t stream) {
    const float* values     = (const float*)d_in[0];
    const float* weight     = (const float*)d_in[1];
    const int*   input_idx  = (const int*)d_in[2];
    const int*   weight_idx = (const int*)d_in[3];
    float*       out        = (float*)d_out;

    int E  = in_sizes[2];
    int NW = in_sizes[1] / (D * D);
    int chunk = (E + NB - 1) / NB;

    // workspace: hist2d[NB*NW] | total[NW] | offsets[NW+1] | pad | perm[2E]
    size_t n_hist = (size_t)NB * NW;
    size_t n_head = n_hist + NW + NW + 1;
    n_head = (n_head + 1) & ~(size_t)1;
    size_t need = (n_head + 2 * (size_t)E) * sizeof(int);

    if (NW > NWMAX || ws_size < need) {
        int total_thr = E * 4;
        int grid = (total_thr + 255) / 256;
        hipLaunchKernelGGL(linear_gather_mv, dim3(grid), dim3(256), 0, stream,
                           values, weight, input_idx, weight_idx, out, E);
        return;
    }

    int* hist2d  = (int*)d_ws;
    int* total   = hist2d + n_hist;
    int* offsets = total + NW;
    int2* perm   = (int2*)((int*)d_ws + n_head);

    hipLaunchKernelGGL(hist_blocks, dim3(NB), dim3(BTS), 0, stream,
                       weight_idx, E, chunk, hist2d, NW);
    hipLaunchKernelGGL(scan_per_bin, dim3(NW), dim3(NB), 0, stream,
                       hist2d, total, NW);
    hipLaunchKernelGGL(scan_bins, dim3(1), dim3(1024), 0, stream,
                       total, offsets, NW);
    hipLaunchKernelGGL(scatter_det, dim3(NB), dim3(BTS), 0, stream,
                       weight_idx, input_idx, E, chunk, hist2d, offsets, perm, NW);
    hipLaunchKernelGGL(bucket_mv, dim3(NW, SEG), dim3(256), 0, stream,
                       values, weight, offsets, perm, out);
}

// Round 10
// 147.598 us; speedup vs baseline: 1.1747x; 1.1747x over previous
//
#include <hip/hip_runtime.h>

// y[e, o] = sum_i weight[widx[e]][o][i] * values[iidx[e]][i]
// E = 1e6, N_W = 1024, D_IN = D_OUT = 16, fp32.
//
// History: R1 naive 137us (weight-gather latency). R2 global-atomic scatter
// 203us. R3-R9: deterministic bucket sort + per-bucket mv; mv stuck 58-70us
// across W-in-LDS / W-pinned / W-global variants -> W never the wall.
// Evidence: R6 (64 random lines in flight per wave) 58us @34% occ beats
// R8/R9 (16 lines/wave) 63-70us @41-52% occ. mv is latency x MLP bound on
// the random line path (x-gather + out-store).
// R10: max MLP with clean stores:
//   - one wave/block; 64-conn batches
//   - gather: lane (g,q) loads quarter q of conn g -> ONE float4 instr
//     requests 16 lines; x4 sub-batches = 64 lines in flight from 4 instrs
//   - staged in wave-local LDS (XOR-swizzled quarters, conflict-free reads,
//     NO __syncthreads)
//   - compute: 16-lane/conn, full-line 64B stores
//   - 1-deep software pipeline: batch n+1 perm+gather in regs during
//     compute of batch n
//   - W row pinned in 16 VGPRs via asm barrier (R8-proven)

#define D 16
#define NWMAX 1024
#define NB 256      // sort chunks
#define BTS 1024    // sort-phase threads per block
#define SEGB 4      // mv segments per bucket

// ---------------- fallback naive kernel (R1, 137us) ----------------
__global__ __launch_bounds__(256) void linear_gather_mv(
    const float* __restrict__ values, const float* __restrict__ weight,
    const int* __restrict__ input_idx, const int* __restrict__ weight_idx,
    float* __restrict__ out, int E)
{
    int tid = blockIdx.x * blockDim.x + threadIdx.x;
    int e = tid >> 2;
    int j = tid & 3;
    if (e >= E) return;
    int ii = input_idx[e];
    int wi = weight_idx[e];
    const float4* xp = (const float4*)(values + (long long)ii * D);
    float4 x0 = xp[0], x1 = xp[1], x2 = xp[2], x3 = xp[3];
    const float4* wp = (const float4*)(weight + (long long)wi * (D * D) + j * (4 * D));
    float4 acc;
    float* accp = (float*)&acc;
    #pragma unroll
    for (int r = 0; r < 4; ++r) {
        float4 w0 = wp[r * 4 + 0], w1 = wp[r * 4 + 1], w2 = wp[r * 4 + 2], w3 = wp[r * 4 + 3];
        accp[r] = w0.x * x0.x + w0.y * x0.y + w0.z * x0.z + w0.w * x0.w
                + w1.x * x1.x + w1.y * x1.y + w1.z * x1.z + w1.w * x1.w
                + w2.x * x2.x + w2.y * x2.y + w2.z * x2.z + w2.w * x2.w
                + w3.x * x3.x + w3.y * x3.y + w3.z * x3.z + w3.w * x3.w;
    }
    ((float4*)out)[(long long)e * 4 + j] = acc;
}

// ---------------- phase 1: per-block private histograms ----------------
__global__ __launch_bounds__(BTS) void hist_blocks(
    const int* __restrict__ widx, int E, int chunk,
    int* __restrict__ hist2d, int NW)
{
    __shared__ int lh[NWMAX];
    for (int i = threadIdx.x; i < NW; i += BTS) lh[i] = 0;
    __syncthreads();
    int s0 = blockIdx.x * chunk;
    int s1 = min(E, s0 + chunk);
    for (int e = s0 + threadIdx.x; e < s1; e += BTS)
        atomicAdd(&lh[widx[e]], 1);
    __syncthreads();
    int* row = hist2d + (long long)blockIdx.x * NW;
    for (int i = threadIdx.x; i < NW; i += BTS) row[i] = lh[i];
}

// ------- phase 2a: per-bin exclusive scan across blocks (parallel) -------
__global__ __launch_bounds__(NB) void scan_per_bin(
    int* __restrict__ hist2d, int* __restrict__ total, int NW)
{
    __shared__ int buf[2 * NB];
    int b = blockIdx.x;
    int t = threadIdx.x;
    int v = hist2d[(long long)t * NW + b];
    buf[t] = v;
    __syncthreads();
    int pin = 0;
    for (int off = 1; off < NB; off <<= 1) {
        int x = buf[pin * NB + t];
        if (t >= off) x += buf[pin * NB + t - off];
        buf[(1 - pin) * NB + t] = x;
        pin = 1 - pin;
        __syncthreads();
    }
    int incl = buf[pin * NB + t];
    hist2d[(long long)t * NW + b] = incl - v;
    if (t == NB - 1) total[b] = incl;
}

// ---------------- phase 2b: scan over bins -> bucket offsets ----------------
__global__ __launch_bounds__(1024) void scan_bins(
    const int* __restrict__ total, int* __restrict__ offsets, int NW)
{
    __shared__ int buf[2 * NWMAX];
    int t = threadIdx.x;
    int v = (t < NW) ? total[t] : 0;
    buf[t] = v;
    __syncthreads();
    int pin = 0;
    for (int off = 1; off < NWMAX; off <<= 1) {
        int x = buf[pin * NWMAX + t];
        if (t >= off) x += buf[pin * NWMAX + t - off];
        buf[(1 - pin) * NWMAX + t] = x;
        pin = 1 - pin;
        __syncthreads();
    }
    int incl = buf[pin * NWMAX + t];
    if (t < NW) {
        offsets[t + 1] = incl;
        if (t == 0) offsets[0] = 0;
    }
}

// ---------------- phase 3: deterministic scatter, LDS cursors ----------------
__global__ __launch_bounds__(BTS) void scatter_det(
    const int* __restrict__ widx, const int* __restrict__ iidx, int E, int chunk,
    const int* __restrict__ hist2d, const int* __restrict__ offsets,
    int2* __restrict__ perm, int NW)
{
    __shared__ int cur[NWMAX];
    int p = blockIdx.x;
    const int* row = hist2d + (long long)p * NW;
    for (int i = threadIdx.x; i < NW; i += BTS)
        cur[i] = offsets[i] + row[i];
    __syncthreads();
    int s0 = p * chunk;
    int s1 = min(E, s0 + chunk);
    for (int e = s0 + threadIdx.x; e < s1; e += BTS) {
        int wi = widx[e];
        int pos = atomicAdd(&cur[wi], 1);
        perm[pos] = make_int2(e, iidx[e]);
    }
}

#define ROWDOT(X0, X1, X2, X3)                                   \
    (w0.x*X0.x + w0.y*X0.y + w0.z*X0.z + w0.w*X0.w               \
   + w1.x*X1.x + w1.y*X1.y + w1.z*X1.z + w1.w*X1.w               \
   + w2.x*X2.x + w2.y*X2.y + w2.z*X2.z + w2.w*X2.w               \
   + w3.x*X3.x + w3.y*X3.y + w3.z*X3.z + w3.w*X3.w)

// ---- phase 4 (R10): one wave/block, 64-conn pipelined batches ----
__global__ __launch_bounds__(64) void bucket_mv(
    const float* __restrict__ values, const float* __restrict__ weight,
    const int* __restrict__ offsets, const int2* __restrict__ perm,
    float* __restrict__ out)
{
    __shared__ float xbuf[64 * D];    // 4KB, wave-local, no barriers
    int b = blockIdx.x;
    int lo = offsets[b], hi = offsets[b + 1];
    int cnt = hi - lo;
    if (cnt == 0) return;
    int per = (cnt + SEGB - 1) / SEGB;
    int s0 = lo + blockIdx.y * per;
    int s1 = min(hi, s0 + per);
    if (s0 >= s1) return;

    int lane = threadIdx.x;      // 0..63
    int sg   = lane >> 4;        // compute subgroup 0..3
    int i    = lane & 15;        // output row owned in compute phase
    int g4   = lane >> 2;        // gather: conn-in-16 (0..15)
    int q    = lane & 3;         // gather: quarter (0..3)

    // W row i pinned in 16 VGPRs (asm barrier prevents sinking/remat)
    const float4* wr = (const float4*)(weight + (long long)b * (D * D) + i * D);
    float4 w0 = wr[0], w1 = wr[1], w2 = wr[2], w3 = wr[3];
    asm volatile("" : "+v"(w0.x), "+v"(w0.y), "+v"(w0.z), "+v"(w0.w),
                      "+v"(w1.x), "+v"(w1.y), "+v"(w1.z), "+v"(w1.w),
                      "+v"(w2.x), "+v"(w2.y), "+v"(w2.z), "+v"(w2.w),
                      "+v"(w3.x), "+v"(w3.y), "+v"(w3.z), "+v"(w3.w));

    // ---- prologue: load batch @ s0 into registers ----
    int2 pe;                        // (e, ii) of conn s0+lane (clamped)
    float4 xq0, xq1, xq2, xq3;      // quarter q of conns {u*16+g4}
    {
        int kl = s0 + lane; if (kl >= s1) kl = s1 - 1;
        pe = perm[kl];
        int iiu;
        iiu = __shfl(pe.y,       g4); xq0 = ((const float4*)(values + (long long)iiu * D))[q];
        iiu = __shfl(pe.y, 16 +  g4); xq1 = ((const float4*)(values + (long long)iiu * D))[q];
        iiu = __shfl(pe.y, 32 +  g4); xq2 = ((const float4*)(values + (long long)iiu * D))[q];
        iiu = __shfl(pe.y, 48 +  g4); xq3 = ((const float4*)(values + (long long)iiu * D))[q];
    }

    for (int k0 = s0; k0 < s1; k0 += 64) {
        // commit current batch regs to LDS (XOR-swizzled quarter slots)
        ((float4*)&xbuf[( 0 + g4) * D])[q ^ 0] = xq0;
        ((float4*)&xbuf[(16 + g4) * D])[q ^ 1] = xq1;
        ((float4*)&xbuf[(32 + g4) * D])[q ^ 2] = xq2;
        ((float4*)&xbuf[(48 + g4) * D])[q ^ 3] = xq3;
        int2 pe_cur = pe;
        int nb = s1 - k0; if (nb > 64) nb = 64;

        // prefetch next batch (perm + 64 x-lines) while computing this one
        int kn = k0 + 64;
        if (kn < s1) {
            int kl = kn + lane; if (kl >= s1) kl = s1 - 1;
            pe = perm[kl];
            int iiu;
            iiu = __shfl(pe.y,       g4); xq0 = ((const float4*)(values + (long long)iiu * D))[q];
            iiu = __shfl(pe.y, 16 +  g4); xq1 = ((const float4*)(values + (long long)iiu * D))[q];
            iiu = __shfl(pe.y, 32 +  g4); xq2 = ((const float4*)(values + (long long)iiu * D))[q];
            iiu = __shfl(pe.y, 48 +  g4); xq3 = ((const float4*)(values + (long long)iiu * D))[q];
        }

        // compute: subgroup sg handles conns sg*16 + t; reads are
        // conflict-free (XOR swizzle) broadcasts; stores are full 64B lines
        #pragma unroll 4
        for (int t = 0; t < 16; ++t) {
            int iw2 = sg * 16 + t;
            const float4* xr = (const float4*)&xbuf[iw2 * D];
            float4 x0 = xr[sg ^ 0];
            float4 x1 = xr[sg ^ 1];
            float4 x2 = xr[sg ^ 2];
            float4 x3 = xr[sg ^ 3];
            float y = ROWDOT(x0, x1, x2, x3);
            int e_t = __shfl(pe_cur.x, iw2);
            if (iw2 < nb)
                out[(long long)e_t * D + i] = y;
        }
    }
}

extern "C" void kernel_launch(void* const* d_in, const int* in_sizes, int n_in,
                              void* d_out, int out_size, void* d_ws, size_t ws_size,
                              hipStream_t stream) {
    const float* values     = (const float*)d_in[0];
    const float* weight     = (const float*)d_in[1];
    const int*   input_idx  = (const int*)d_in[2];
    const int*   weight_idx = (const int*)d_in[3];
    float*       out        = (float*)d_out;

    int E  = in_sizes[2];
    int NW = in_sizes[1] / (D * D);
    int chunk = (E + NB - 1) / NB;

    // workspace: hist2d[NB*NW] | total[NW] | offsets[NW+1] | pad | perm[2E]
    size_t n_hist = (size_t)NB * NW;
    size_t n_head = n_hist + NW + NW + 1;
    n_head = (n_head + 1) & ~(size_t)1;
    size_t need = (n_head + 2 * (size_t)E) * sizeof(int);

    if (NW > NWMAX || ws_size < need) {
        int total_thr = E * 4;
        int grid = (total_thr + 255) / 256;
        hipLaunchKernelGGL(linear_gather_mv, dim3(grid), dim3(256), 0, stream,
                           values, weight, input_idx, weight_idx, out, E);
        return;
    }

    int* hist2d  = (int*)d_ws;
    int* total   = hist2d + n_hist;
    int* offsets = total + NW;
    int2* perm   = (int2*)((int*)d_ws + n_head);

    hipLaunchKernelGGL(hist_blocks, dim3(NB), dim3(BTS), 0, stream,
                       weight_idx, E, chunk, hist2d, NW);
    hipLaunchKernelGGL(scan_per_bin, dim3(NW), dim3(NB), 0, stream,
                       hist2d, total, NW);
    hipLaunchKernelGGL(scan_bins, dim3(1), dim3(1024), 0, stream,
                       total, offsets, NW);
    hipLaunchKernelGGL(scatter_det, dim3(NB), dim3(BTS), 0, stream,
                       weight_idx, input_idx, E, chunk, hist2d, offsets, perm, NW);
    hipLaunchKernelGGL(bucket_mv, dim3(NW, SEGB), dim3(64), 0, stream,
                       values, weight, offsets, perm, out);
}